// Round 2
// baseline (1793.498 us; speedup 1.0000x reference)
//
#include <hip/hip_runtime.h>
#include <stdint.h>

#define Bdim 1024
#define Tdim 512
#define DIN  64
#define DOUT 32
#define DZ   32
#define DH   128
#define Msamp 4
#define NWG  256          // Bdim / Msamp
#define NTHR 512
#define SP   136          // padded LDS row stride (bf16 elems): breaks 32-way bank conflicts

// Set to 1 if the reference dataset was generated with legacy (non-partitionable) threefry.
#define EPS_LEGACY 0

using s16x8 = __attribute__((ext_vector_type(8))) short;   // 8 x bf16 (4 VGPRs)
using f32x4 = __attribute__((ext_vector_type(4))) float;

#define MFMA(a, b, c) __builtin_amdgcn_mfma_f32_16x16x32_bf16((a), (b), (c), 0, 0, 0)

// ---------------- threefry2x32 (JAX/Random123, 20 rounds) ----------------
__host__ __device__ inline void tf2x32(unsigned k0, unsigned k1, unsigned c0, unsigned c1,
                                       unsigned &o0, unsigned &o1) {
  unsigned ks2 = k0 ^ k1 ^ 0x1BD11BDAu;
  unsigned x0 = c0 + k0, x1 = c1 + k1;
#define TFR(r) { x0 += x1; x1 = (x1 << (r)) | (x1 >> (32 - (r))); x1 ^= x0; }
  TFR(13) TFR(15) TFR(26) TFR(6)
  x0 += k1;  x1 += ks2 + 1u;
  TFR(17) TFR(29) TFR(16) TFR(24)
  x0 += ks2; x1 += k0 + 2u;
  TFR(13) TFR(15) TFR(26) TFR(6)
  x0 += k0;  x1 += k1 + 3u;
  TFR(17) TFR(29) TFR(16) TFR(24)
  x0 += k1;  x1 += ks2 + 4u;
  TFR(13) TFR(15) TFR(26) TFR(6)
  x0 += ks2; x1 += k0 + 5u;
#undef TFR
  o0 = x0; o1 = x1;
}

// XLA ErfInv32 (Giles polynomial) — matches lax.erf_inv expansion
__device__ inline float erfinv_xla(float x) {
  float w = -log1pf(-x * x);
  float p;
  if (w < 5.0f) {
    w -= 2.5f;
    p = 2.81022636e-08f;
    p = fmaf(p, w, 3.43273939e-07f);
    p = fmaf(p, w, -3.5233877e-06f);
    p = fmaf(p, w, -4.39150654e-06f);
    p = fmaf(p, w, 0.00021858087f);
    p = fmaf(p, w, -0.00125372503f);
    p = fmaf(p, w, -0.00417768164f);
    p = fmaf(p, w, 0.246640727f);
    p = fmaf(p, w, 1.50140941f);
  } else {
    w = sqrtf(w) - 3.0f;
    p = -0.000200214257f;
    p = fmaf(p, w, 0.000100950558f);
    p = fmaf(p, w, 0.00134934322f);
    p = fmaf(p, w, -0.00367342844f);
    p = fmaf(p, w, 0.00573950773f);
    p = fmaf(p, w, -0.0076224613f);
    p = fmaf(p, w, 0.00943887047f);
    p = fmaf(p, w, 1.00167406f);
    p = fmaf(p, w, 2.83297682f);
  }
  return p * x;
}

__device__ inline float bits_to_normal(unsigned bits) {
  float f = __uint_as_float((bits >> 9) | 0x3f800000u) - 1.0f;  // [0,1)
  float u = f * 2.0f - 0.99999994f;                             // [lo, 1)  (hi-lo == 2.0f exactly)
  u = fmaxf(u, -0.99999994f);
  return 1.41421356f * erfinv_xla(u);                           // sqrt(2)*erfinv
}

// partitionable path (jax >= 0.4.36 default): counter = (hi32(i), lo32(i)),
// 32-bit output is the XOR-FOLD of both cipher words: bits = out0 ^ out1.
__device__ inline float jax_normal_part(unsigned k0, unsigned k1, unsigned idx) {
  unsigned o0, o1;
  tf2x32(k0, k1, 0u, idx, o0, o1);
  return bits_to_normal(o0 ^ o1);
}
// legacy path: bits[i<N/2] = cipher(i, i+N/2).x0 ; bits[i>=N/2] = cipher(i-N/2, i).x1
__device__ inline float jax_normal_legacy(unsigned k0, unsigned k1, unsigned idx, unsigned half) {
  unsigned c0 = idx < half ? idx : idx - half;
  unsigned o0, o1;
  tf2x32(k0, k1, c0, c0 + half, o0, o1);
  return bits_to_normal(idx < half ? o0 : o1);
}
__device__ inline float jax_normal(unsigned k0, unsigned k1, unsigned idx, unsigned half) {
#if EPS_LEGACY
  return jax_normal_legacy(k0, k1, idx, half);
#else
  (void)half;
  return jax_normal_part(k0, k1, idx);
#endif
}

// ---------------- small helpers ----------------
__device__ inline short f2bf(float x) {  // RNE float->bf16 bits
  unsigned u = __float_as_uint(x);
  u = (u + 0x7fffu + ((u >> 16) & 1u)) >> 16;
  return (short)u;
}
__device__ inline float clampf(float v) { return fminf(fmaxf(v, -10.0f), 2.0f); }
__device__ inline float tanh_fast(float v) {
  float e = __expf(2.0f * v);
  return 1.0f - __fdividef(2.0f, e + 1.0f);
}

// Load one MFMA B-fragment (16 cols x 32 k) of fp32 weight W (K x N, row-major) as bf16.
// B-frag layout: lane l holds B[k = kt*32 + (l>>4)*8 + e][n = nt*16 + (l&15)], e=0..7.
// (Any consistent A/B k-permutation yields the correct dot product.)
__device__ inline s16x8 load_frag(const float* __restrict__ W, int N, int kt, int nt, int lane) {
  int k0 = kt * 32 + ((lane >> 4) << 3);
  int n  = nt * 16 + (lane & 15);
  s16x8 f;
#pragma unroll
  for (int e = 0; e < 8; ++e) f[e] = f2bf(W[(size_t)(k0 + e) * N + n]);
  return f;
}

// A-fragment from LDS activation buffer (row-major [16][SP] bf16):
// lane l reads row (l&15), k = kt*32 + (l>>4)*8 .. +8  -> one ds_read_b128, 16B aligned.
#define AF(buf, kt) (*(const s16x8*)&(buf)[(lane & 15) * SP + (kt) * 32 + ((lane >> 4) << 3)])

// D layout (verified m89): lane l holds D[(l>>4)*4 + r][l&15], r=0..3.
// With Msamp=4 the valid sample rows 0..3 live entirely in lanes 0..15.
__device__ __forceinline__ void epi_tanh(const f32x4 c, short* ob, int nt, const float* bp, int lane) {
  if (lane < 16) {
    float bv = bp[nt * 16 + lane];
#pragma unroll
    for (int r = 0; r < 4; ++r) ob[r * SP + nt * 16 + lane] = f2bf(tanh_fast(c[r] + bv));
  }
}

// ---------------- main persistent kernel ----------------
__global__ __launch_bounds__(NTHR, 2) void dssm_main(
    const float* __restrict__ gx, const float* __restrict__ gy,
    const float* __restrict__ pW1, const float* __restrict__ pb1,
    const float* __restrict__ pW2, const float* __restrict__ pb2,
    const float* __restrict__ pW3, const float* __restrict__ pb3,
    const float* __restrict__ qW1, const float* __restrict__ qb1,
    const float* __restrict__ qW2, const float* __restrict__ qb2,
    const float* __restrict__ qW3, const float* __restrict__ qb3,
    const float* __restrict__ eW1, const float* __restrict__ eb1,
    const float* __restrict__ eW2, const float* __restrict__ eb2,
    const float* __restrict__ eW3, const float* __restrict__ eb3,
    const float* __restrict__ z0mu, const float* __restrict__ z0lv,
    float* __restrict__ gout, float* __restrict__ gws,
    unsigned ka0, unsigned ka1, unsigned kb0, unsigned kb1)
{
  __shared__ __align__(16) short in_pq[16 * SP];                 // [z(32) | x(64) | y(32)]
  __shared__ __align__(16) short hpa[16 * SP], hpb[16 * SP];     // prior hidden
  __shared__ __align__(16) short hqa[16 * SP], hqb[16 * SP];     // post hidden
  __shared__ __align__(16) short hea[16 * SP], heb[16 * SP];     // emit hidden
  __shared__ float out_p[4 * 64], out_q[4 * 64], emit_o[4 * 64]; // fp32 heads
  __shared__ float bias[960];
  __shared__ float red[16];

  const int tid  = threadIdx.x;
  const int wv   = tid >> 6;
  const int lane = tid & 63;
  const int wg   = blockIdx.x;
  const int base = wg * Msamp;

  // ---- prologue: zero activation LDS (rows 4..15 stay 0 forever), biases ----
  for (int i = tid; i < 16 * SP; i += NTHR) {
    in_pq[i] = 0; hpa[i] = 0; hpb[i] = 0; hqa[i] = 0; hqb[i] = 0; hea[i] = 0; heb[i] = 0;
  }
  if (tid < 128) {
    bias[tid] = pb1[tid];       bias[128 + tid] = pb2[tid];
    bias[320 + tid] = qb1[tid]; bias[448 + tid] = qb2[tid];
    bias[640 + tid] = eb1[tid]; bias[768 + tid] = eb2[tid];
  }
  if (tid < 64) { bias[256 + tid] = pb3[tid]; bias[576 + tid] = qb3[tid]; bias[896 + tid] = eb3[tid]; }

  // ---- weights -> register-resident B-fragments ----
  s16x8 wf[27];
#pragma unroll
  for (int i = 0; i < 27; ++i) wf[i] = (s16x8)(short)0;
  if (wv < 4) {
#pragma unroll
    for (int j = 0; j < 2; ++j) {
#pragma unroll
      for (int kt = 0; kt < 3; ++kt) wf[j * 3 + kt]     = load_frag(pW1, 128, kt, 2 * wv + j, lane);
#pragma unroll
      for (int kt = 0; kt < 4; ++kt) wf[6 + j * 4 + kt] = load_frag(pW2, 128, kt, 2 * wv + j, lane);
    }
#pragma unroll
    for (int kt = 0; kt < 4; ++kt) wf[14 + kt] = load_frag(pW3, 64, kt, wv, lane);
    wf[18] = load_frag(eW1, 128, 0, wv, lane);
#pragma unroll
    for (int kt = 0; kt < 4; ++kt) wf[19 + kt] = load_frag(eW2, 128, kt, wv, lane);
#pragma unroll
    for (int kt = 0; kt < 4; ++kt) wf[23 + kt] = load_frag(eW3, 64, kt, wv, lane);
  } else {
    const int qw = wv - 4;
#pragma unroll
    for (int j = 0; j < 2; ++j) {
#pragma unroll
      for (int kt = 0; kt < 4; ++kt) wf[j * 4 + kt]     = load_frag(qW1, 128, kt, 2 * qw + j, lane);
#pragma unroll
      for (int kt = 0; kt < 4; ++kt) wf[8 + j * 4 + kt] = load_frag(qW2, 128, kt, 2 * qw + j, lane);
    }
#pragma unroll
    for (int kt = 0; kt < 4; ++kt) wf[16 + kt] = load_frag(qW3, 64, kt, qw, lane);
    wf[20] = load_frag(eW1, 128, 0, wv, lane);
#pragma unroll
    for (int kt = 0; kt < 4; ++kt) wf[21 + kt] = load_frag(eW2, 128, kt, wv, lane);
  }
  __syncthreads();

  // ---- t=0 inputs + z0 ----
  float y_cur = 0.0f;
  if (tid < 256) {
    int s = tid >> 6, j = tid & 63;
    float v = gx[((size_t)(base + s) * Tdim + 0) * DIN + j];
    in_pq[s * SP + 32 + j] = f2bf(v);
  } else if (tid < 384) {
    int i = tid - 256, s = i >> 5, j = i & 31;
    y_cur = gy[((size_t)(base + s) * Tdim + 0) * DOUT + j];
    in_pq[s * SP + 96 + j] = f2bf(y_cur);
  }
  if (tid < 128) {
    int s = tid >> 5, zd = tid & 31;
    unsigned idx = (unsigned)(base + s) * 32u + (unsigned)zd;   // flat over (B, DZ)
    float e0 = jax_normal(ka0, ka1, idx, 16384u);
    float lv = clampf(z0lv[zd]);
    float z  = z0mu[zd] + __expf(0.5f * lv) * e0;
    in_pq[s * SP + zd] = f2bf(z);
  }
  __syncthreads();

  float nll_acc = 0.0f, kl_acc = 0.0f;
  float xv = 0.0f, yv = 0.0f;

#pragma unroll 1
  for (int t = 0; t < Tdim; ++t) {
    // issue next-step global loads (land by phase 4)
    if (t + 1 < Tdim) {
      if (tid < 256) {
        int s = tid >> 6, j = tid & 63;
        xv = gx[((size_t)(base + s) * Tdim + (t + 1)) * DIN + j];
      } else if (tid < 384) {
        int i = tid - 256, s = i >> 5, j = i & 31;
        yv = gy[((size_t)(base + s) * Tdim + (t + 1)) * DOUT + j];
      }
    }

    // ---- phase 1: prior/post layer 1 ----
    if (wv < 4) {
      s16x8 a0 = AF(in_pq, 0), a1 = AF(in_pq, 1), a2 = AF(in_pq, 2);
      f32x4 c0 = {0, 0, 0, 0}, c1 = {0, 0, 0, 0};
      c0 = MFMA(a0, wf[0], c0); c0 = MFMA(a1, wf[1], c0); c0 = MFMA(a2, wf[2], c0);
      c1 = MFMA(a0, wf[3], c1); c1 = MFMA(a1, wf[4], c1); c1 = MFMA(a2, wf[5], c1);
      epi_tanh(c0, hpa, 2 * wv + 0, &bias[0], lane);
      epi_tanh(c1, hpa, 2 * wv + 1, &bias[0], lane);
    } else {
      const int qw = wv - 4;
      s16x8 a0 = AF(in_pq, 0), a1 = AF(in_pq, 1), a2 = AF(in_pq, 2), a3 = AF(in_pq, 3);
      f32x4 c0 = {0, 0, 0, 0}, c1 = {0, 0, 0, 0};
      c0 = MFMA(a0, wf[0], c0); c0 = MFMA(a1, wf[1], c0); c0 = MFMA(a2, wf[2], c0); c0 = MFMA(a3, wf[3], c0);
      c1 = MFMA(a0, wf[4], c1); c1 = MFMA(a1, wf[5], c1); c1 = MFMA(a2, wf[6], c1); c1 = MFMA(a3, wf[7], c1);
      epi_tanh(c0, hqa, 2 * qw + 0, &bias[320], lane);
      epi_tanh(c1, hqa, 2 * qw + 1, &bias[320], lane);
    }
    __syncthreads();

    // ---- phase 2: layer 2 ----
    if (wv < 4) {
      s16x8 a0 = AF(hpa, 0), a1 = AF(hpa, 1), a2 = AF(hpa, 2), a3 = AF(hpa, 3);
      f32x4 c0 = {0, 0, 0, 0}, c1 = {0, 0, 0, 0};
      c0 = MFMA(a0, wf[6], c0);  c0 = MFMA(a1, wf[7], c0);  c0 = MFMA(a2, wf[8], c0);  c0 = MFMA(a3, wf[9], c0);
      c1 = MFMA(a0, wf[10], c1); c1 = MFMA(a1, wf[11], c1); c1 = MFMA(a2, wf[12], c1); c1 = MFMA(a3, wf[13], c1);
      epi_tanh(c0, hpb, 2 * wv + 0, &bias[128], lane);
      epi_tanh(c1, hpb, 2 * wv + 1, &bias[128], lane);
    } else {
      const int qw = wv - 4;
      s16x8 a0 = AF(hqa, 0), a1 = AF(hqa, 1), a2 = AF(hqa, 2), a3 = AF(hqa, 3);
      f32x4 c0 = {0, 0, 0, 0}, c1 = {0, 0, 0, 0};
      c0 = MFMA(a0, wf[8], c0);  c0 = MFMA(a1, wf[9], c0);  c0 = MFMA(a2, wf[10], c0); c0 = MFMA(a3, wf[11], c0);
      c1 = MFMA(a0, wf[12], c1); c1 = MFMA(a1, wf[13], c1); c1 = MFMA(a2, wf[14], c1); c1 = MFMA(a3, wf[15], c1);
      epi_tanh(c0, hqb, 2 * qw + 0, &bias[448], lane);
      epi_tanh(c1, hqb, 2 * qw + 1, &bias[448], lane);
    }
    __syncthreads();

    // ---- phase 3: layer 3 (linear heads, fp32 to LDS) ----
    if (wv < 4) {
      s16x8 a0 = AF(hpb, 0), a1 = AF(hpb, 1), a2 = AF(hpb, 2), a3 = AF(hpb, 3);
      f32x4 c = {0, 0, 0, 0};
      c = MFMA(a0, wf[14], c); c = MFMA(a1, wf[15], c); c = MFMA(a2, wf[16], c); c = MFMA(a3, wf[17], c);
      if (lane < 16) {
        float bv = bias[256 + wv * 16 + lane];
#pragma unroll
        for (int r = 0; r < 4; ++r) out_p[r * 64 + wv * 16 + lane] = c[r] + bv;
      }
    } else {
      const int qw = wv - 4;
      s16x8 a0 = AF(hqb, 0), a1 = AF(hqb, 1), a2 = AF(hqb, 2), a3 = AF(hqb, 3);
      f32x4 c = {0, 0, 0, 0};
      c = MFMA(a0, wf[16], c); c = MFMA(a1, wf[17], c); c = MFMA(a2, wf[18], c); c = MFMA(a3, wf[19], c);
      if (lane < 16) {
        float bv = bias[576 + qw * 16 + lane];
#pragma unroll
        for (int r = 0; r < 4; ++r) out_q[r * 64 + qw * 16 + lane] = c[r] + bv;
      }
    }
    __syncthreads();

    // ---- phase 4: write x/y(t+1) to LDS; sample z_t; accumulate KL ----
    if (t + 1 < Tdim) {
      if (tid < 256) {
        int s = tid >> 6, j = tid & 63;
        in_pq[s * SP + 32 + j] = f2bf(xv);
      } else if (tid < 384) {
        int i = tid - 256, s = i >> 5, j = i & 31;
        in_pq[s * SP + 96 + j] = f2bf(yv);
      }
    }
    if (tid < 128) {
      int s = tid >> 5, zd = tid & 31;
      float mu_q = out_q[s * 64 + zd];
      float lv_q = clampf(out_q[s * 64 + 32 + zd]);
      float mu_p = out_p[s * 64 + zd];
      float lv_p = clampf(out_p[s * 64 + 32 + zd]);
      unsigned idx = (unsigned)t * 32768u + (unsigned)(base + s) * 32u + (unsigned)zd; // flat (T,B,DZ)
      float e = jax_normal(kb0, kb1, idx, 8388608u);
      float z = mu_q + __expf(0.5f * lv_q) * e;
      in_pq[s * SP + zd] = f2bf(z);
      float vq = __expf(lv_q), vp = __expf(lv_p);
      float dm = mu_q - mu_p;
      kl_acc += lv_p - lv_q + (vq + dm * dm) / (vp + 1e-12f);
    }
    __syncthreads();

    // ---- phase 5: emit layer 1 (K=32, z) ----
    {
      s16x8 az = AF(in_pq, 0);
      f32x4 c = {0, 0, 0, 0};
      if (wv < 4) c = MFMA(az, wf[18], c); else c = MFMA(az, wf[20], c);
      epi_tanh(c, hea, wv, &bias[640], lane);
    }
    __syncthreads();

    // ---- phase 6: emit layer 2 ----
    {
      s16x8 a0 = AF(hea, 0), a1 = AF(hea, 1), a2 = AF(hea, 2), a3 = AF(hea, 3);
      f32x4 c = {0, 0, 0, 0};
      if (wv < 4) { c = MFMA(a0, wf[19], c); c = MFMA(a1, wf[20], c); c = MFMA(a2, wf[21], c); c = MFMA(a3, wf[22], c); }
      else        { c = MFMA(a0, wf[21], c); c = MFMA(a1, wf[22], c); c = MFMA(a2, wf[23], c); c = MFMA(a3, wf[24], c); }
      epi_tanh(c, heb, wv, &bias[768], lane);
    }
    __syncthreads();

    // ---- phase 7: emit layer 3 -> emit_o + mu_y global store ----
    if (wv < 4) {
      s16x8 a0 = AF(heb, 0), a1 = AF(heb, 1), a2 = AF(heb, 2), a3 = AF(heb, 3);
      f32x4 c = {0, 0, 0, 0};
      c = MFMA(a0, wf[23], c); c = MFMA(a1, wf[24], c); c = MFMA(a2, wf[25], c); c = MFMA(a3, wf[26], c);
      if (lane < 16) {
        float bv = bias[896 + wv * 16 + lane];
#pragma unroll
        for (int r = 0; r < 4; ++r) {
          float v = c[r] + bv;
          emit_o[r * 64 + wv * 16 + lane] = v;
          if (wv < 2)  // mu_y = first 32 cols
            gout[((size_t)(base + r) * Tdim + t) * DOUT + wv * 16 + lane] = v;
        }
      }
    }
    __syncthreads();

    // ---- phase 8: NLL accumulation (no barrier needed; overlaps next phase 1) ----
    if (tid >= 256 && tid < 384) {
      int i = tid - 256, s = i >> 5, j = i & 31;
      float mu = emit_o[s * 64 + j];
      float lv = clampf(emit_o[s * 64 + 32 + j]);
      float d  = y_cur - mu;
      nll_acc += lv + d * d * __expf(-lv);
    }
    y_cur = yv;
  }

  // ---- per-WG reduction of KL/NLL partials ----
  float vn = nll_acc, vk = kl_acc;
#pragma unroll
  for (int o = 32; o > 0; o >>= 1) { vn += __shfl_down(vn, o, 64); vk += __shfl_down(vk, o, 64); }
  if (lane == 0) { red[wv] = vn; red[8 + wv] = vk; }
  __syncthreads();
  if (tid == 0) {
    float sn = 0.0f, sk = 0.0f;
#pragma unroll
    for (int i = 0; i < 8; ++i) { sn += red[i]; sk += red[8 + i]; }
    gws[wg] = sn;
    gws[NWG + wg] = sk;
  }
}

// ---------------- finalize: reduce 256 partials -> total/nll/kl ----------------
__global__ void dssm_fin(const float* __restrict__ gws, float* __restrict__ gout) {
  __shared__ float s[16];
  int tid = threadIdx.x;              // 256 threads
  float vn = gws[tid], vk = gws[NWG + tid];
#pragma unroll
  for (int o = 32; o > 0; o >>= 1) { vn += __shfl_down(vn, o, 64); vk += __shfl_down(vk, o, 64); }
  int wv = tid >> 6, lane = tid & 63;
  if (lane == 0) { s[wv] = vn; s[8 + wv] = vk; }
  __syncthreads();
  if (tid == 0) {
    float sn = 0.0f, sk = 0.0f;
#pragma unroll
    for (int i = 0; i < 4; ++i) { sn += s[i]; sk += s[8 + i]; }
    const float inv = 1.0f / (float)((size_t)Bdim * Tdim);
    float nll = 0.5f * (sn * inv + (float)DOUT * 1.8378770664093453f);  // + sum_j LOG2PI
    float kl  = 0.5f * (sk * inv - (float)DZ);                          // the "-1" per latent dim
    size_t o0 = (size_t)Bdim * Tdim * DOUT;
    gout[o0 + 0] = nll + kl;
    gout[o0 + 1] = nll;
    gout[o0 + 2] = kl;
  }
}

extern "C" void kernel_launch(void* const* d_in, const int* in_sizes, int n_in,
                              void* d_out, int out_size, void* d_ws, size_t ws_size,
                              hipStream_t stream) {
  (void)in_sizes; (void)n_in; (void)out_size; (void)ws_size;
  const float* gx  = (const float*)d_in[0];
  const float* gy  = (const float*)d_in[1];
  const float* pW1 = (const float*)d_in[2];  const float* pb1 = (const float*)d_in[3];
  const float* pW2 = (const float*)d_in[4];  const float* pb2 = (const float*)d_in[5];
  const float* pW3 = (const float*)d_in[6];  const float* pb3 = (const float*)d_in[7];
  const float* qW1 = (const float*)d_in[8];  const float* qb1 = (const float*)d_in[9];
  const float* qW2 = (const float*)d_in[10]; const float* qb2 = (const float*)d_in[11];
  const float* qW3 = (const float*)d_in[12]; const float* qb3 = (const float*)d_in[13];
  const float* eW1 = (const float*)d_in[14]; const float* eb1 = (const float*)d_in[15];
  const float* eW2 = (const float*)d_in[16]; const float* eb2 = (const float*)d_in[17];
  const float* eW3 = (const float*)d_in[18]; const float* eb3 = (const float*)d_in[19];
  const float* z0mu = (const float*)d_in[20];
  const float* z0lv = (const float*)d_in[21];
  float* gout = (float*)d_out;
  float* gws  = (float*)d_ws;

  // fold_in(key(42), 0) and fold_in(key(42), 1): threefry(key=(0,42), count=(0,data))
  unsigned ka0, ka1, kb0, kb1;
  tf2x32(0u, 42u, 0u, 0u, ka0, ka1);   // eps0 key (B, DZ)
  tf2x32(0u, 42u, 0u, 1u, kb0, kb1);   // eps key (T, B, DZ)

  dssm_main<<<NWG, NTHR, 0, stream>>>(gx, gy,
      pW1, pb1, pW2, pb2, pW3, pb3,
      qW1, qb1, qW2, qb2, qW3, qb3,
      eW1, eb1, eW2, eb2, eW3, eb3,
      z0mu, z0lv, gout, gws, ka0, ka1, kb0, kb1);
  dssm_fin<<<1, 256, 0, stream>>>(gws, gout);
}